// Round 8
// baseline (224.960 us; speedup 1.0000x reference)
//
#include <hip/hip_runtime.h>

typedef __bf16 bf16;
typedef __bf16 bf16x8 __attribute__((ext_vector_type(8)));
typedef __bf16 bf16x4 __attribute__((ext_vector_type(4)));
typedef float  f32x4  __attribute__((ext_vector_type(4)));

#define D_MODEL 1024
#define S_LEN   2048
#define NHEAD   16
#define DHEAD   64
#define BATCH   2
#define MROWS   (BATCH * S_LEN)   // 4096

// 0.125 (1/sqrt(dhead)) * log2(e): Q pre-scaled so softmax runs in exp2 domain
#define QSCALE 0.18033688011112042f

// ---- async global->LDS, 16B per lane. lds_base must be wave-uniform; HW
// writes lane i's data at lds_base + i*16 (guide §5 caveat).
__device__ __forceinline__ void gld_lds16(const void* g, void* lds_base) {
    __builtin_amdgcn_global_load_lds(
        (const __attribute__((address_space(1))) void*)g,
        (__attribute__((address_space(3))) void*)lds_base, 16, 0, 0);
}

// == prep: transpose+cast 4 weights (z<4) | cast x (z==4) | zero out (z==5) ==
__global__ void prep_kernel(const float* __restrict__ x,
                            const float* __restrict__ W0, const float* __restrict__ W1,
                            const float* __restrict__ W2, const float* __restrict__ W3,
                            bf16* __restrict__ xb, bf16* __restrict__ Wt,
                            float* __restrict__ outz) {
    int tx = threadIdx.x, ty = threadIdx.y;   // (32, 8)
    if (blockIdx.z == 5) {
        // zero d_out (4096x1024 f32): split-K gemm1 accumulates via atomicAdd
        int tid = ty * 32 + tx;
        size_t base = ((size_t)blockIdx.y * 32 + blockIdx.x) * 4096;
#pragma unroll
        for (int j = 0; j < 4; j++)
            *(f32x4*)(outz + base + (size_t)(j * 256 + tid) * 4) =
                (f32x4){0.f, 0.f, 0.f, 0.f};
        return;
    }
    if (blockIdx.z == 4) {
        int tid = ty * 32 + tx;
        size_t base = ((size_t)blockIdx.y * 32 + blockIdx.x) * 4096;
#pragma unroll
        for (int j = 0; j < 4; j++) {
            size_t i = base + (size_t)(j * 256 + tid) * 4;
            f32x4 v = *(const f32x4*)(x + i);
            bf16x4 o;
            o[0] = (bf16)v[0]; o[1] = (bf16)v[1]; o[2] = (bf16)v[2]; o[3] = (bf16)v[3];
            *(bf16x4*)(xb + i) = o;
        }
        return;
    }
    __shared__ float tile[32][33];
    const float* W = (blockIdx.z == 0) ? W0 : (blockIdx.z == 1) ? W1
                   : (blockIdx.z == 2) ? W2 : W3;
    int n0 = blockIdx.x * 32, k0 = blockIdx.y * 32;
#pragma unroll
    for (int j = 0; j < 4; j++)
        tile[ty + 8 * j][tx] = W[(size_t)(k0 + ty + 8 * j) * D_MODEL + n0 + tx];
    __syncthreads();
    bf16* out = Wt + (size_t)blockIdx.z * D_MODEL * D_MODEL;
#pragma unroll
    for (int j = 0; j < 4; j++)
        out[(size_t)(n0 + ty + 8 * j) * D_MODEL + k0 + tx] = (bf16)tile[tx][ty + 8 * j];
}

// ================== gemm0: QKV projections (round-6 proven) ==================
// BM=128 BN=128 BK=32, 4 waves 2x2, per-wave 64x64 (acc[4][4], 16 MFMA per 4
// staged loads). Triple-buffered, prefetch depth 2, COUNTED vmcnt(4): own
// stage(ks) complete, newest stage(ks+1) stays in flight across the barrier.
// Staging pre-swizzles the GLOBAL k-group (LDS dest linear, required by
// global_load_lds): slot kg of row r holds k-group kg ^ ((r>>1)&3); read slot
// quad ^ ((m16>>1)&3) -> per-phase bank-starts 8 values x 2 lanes = 2-way =
// free (measured 0 conflicts, round 6). Measured 44.2 us / MfmaUtil 21.
// (Round-7 BK=64/BN=64/depth-1 variant regressed to 50.8: depth-1 vmcnt(0)
// exposes full load latency per step; BN=64 raises staged-bytes/FLOP 1.5x.)
__global__ __launch_bounds__(256, 3) void gemm0_kernel(
    const bf16* __restrict__ A, const bf16* __restrict__ Bt,
    const float* __restrict__ b0, const float* __restrict__ b1, const float* __restrict__ b2,
    bf16* __restrict__ Qo, bf16* __restrict__ Ko, bf16* __restrict__ Vto) {
    __shared__ bf16 sA[3][128 * 32];
    __shared__ bf16 sB[3][128 * 32];
    const int t = threadIdx.x;
    const int wave = t >> 6, lane = t & 63;
    const int quad = lane >> 4, m16 = lane & 15;
    const int wrow = (wave >> 1) * 64, wcol = (wave & 1) * 64;
    const int row0 = blockIdx.y * 128, col0 = blockIdx.x * 128;
    constexpr int NK = D_MODEL / 32;

    f32x4 acc[4][4];
#pragma unroll
    for (int i = 0; i < 4; i++)
#pragma unroll
        for (int j = 0; j < 4; j++) acc[i][j] = (f32x4){0.f, 0.f, 0.f, 0.f};

    auto stage = [&](int kk, int buf) {
#pragma unroll
        for (int i = 0; i < 2; i++) {
            int cb = i * 256 + wave * 64;       // wave-uniform chunk base
            int c  = cb + lane;
            int r  = c >> 2, kg = c & 3;        // tile row, LDS slot
            int gk = kg ^ ((r >> 1) & 3);       // swizzled global k-group
            gld_lds16(A + (size_t)(row0 + r) * D_MODEL + kk * 32 + gk * 8,
                      (char*)&sA[buf][0] + cb * 16);
        }
#pragma unroll
        for (int i = 0; i < 2; i++) {
            int cb = i * 256 + wave * 64;
            int c  = cb + lane;
            int r  = c >> 2, kg = c & 3;
            int gk = kg ^ ((r >> 1) & 3);
            gld_lds16(Bt + (size_t)(col0 + r) * D_MODEL + kk * 32 + gk * 8,
                      (char*)&sB[buf][0] + cb * 16);
        }
    };

    stage(0, 0);
    stage(1, 1);

    const int sx = (m16 >> 1) & 3;    // row-derived slot swizzle (wave-inv.)
    for (int ks = 0; ks < NK; ++ks) {
        if (ks + 1 < NK)
            asm volatile("s_waitcnt vmcnt(4)\n\ts_barrier" ::: "memory");
        else
            asm volatile("s_waitcnt vmcnt(0)\n\ts_barrier" ::: "memory");
        if (ks + 2 < NK) stage(ks + 2, (ks + 2) % 3);

        const int cur = ks % 3;
        const int gg = (quad ^ sx) * 8;
        bf16x8 af[4], bfr[4];
#pragma unroll
        for (int mi = 0; mi < 4; mi++)
            af[mi] = *(const bf16x8*)&sA[cur][(wrow + mi * 16 + m16) * 32 + gg];
#pragma unroll
        for (int ni = 0; ni < 4; ni++)
            bfr[ni] = *(const bf16x8*)&sB[cur][(wcol + ni * 16 + m16) * 32 + gg];
#pragma unroll
        for (int mi = 0; mi < 4; mi++)
#pragma unroll
            for (int ni = 0; ni < 4; ni++)
                acc[mi][ni] = __builtin_amdgcn_mfma_f32_16x16x32_bf16(
                    af[mi], bfr[ni], acc[mi][ni], 0, 0, 0);
    }

    // epilogue (C/D: col = lane&15, row = quad*4 + reg; m89-verified).
    int sel = col0 >> 10;   // uniform per block (1024 % 128 == 0)
    const float* bias_arr = (sel == 0) ? b0 : (sel == 1) ? b1 : b2;
#pragma unroll
    for (int mi = 0; mi < 4; mi++) {
        int s0g = row0 + wrow + mi * 16 + quad * 4;   // global M-row base
        int b = s0g >> 11, ss0 = s0g & 2047;
#pragma unroll
        for (int ni = 0; ni < 4; ni++) {
            int col = col0 + wcol + ni * 16 + m16;
            int cn = col & 1023;
            int h = cn >> 6, d = cn & 63;
            float bias = bias_arr[cn];
            if (sel < 2) {
                bf16* dst = (sel == 0) ? Qo : Ko;
                float scl = (sel == 0) ? QSCALE : 1.0f;
                size_t base = (((size_t)b * NHEAD + h) * S_LEN);
#pragma unroll
                for (int r = 0; r < 4; r++)
                    dst[(base + ss0 + r) * DHEAD + d] = (bf16)((acc[mi][ni][r] + bias) * scl);
            } else {
                bf16x4 pk;
#pragma unroll
                for (int r = 0; r < 4; r++) pk[r] = (bf16)(acc[mi][ni][r] + bias);
                *(bf16x4*)(Vto + (((size_t)b * NHEAD + h) * DHEAD + d) * S_LEN + ss0) = pk;
            }
        }
    }
}

// ============ gemm1: output projection, block-level split-K x4 ==============
// Round-7 closure: gemm1 ~35.6 us at 246 TF -- its tiny BN=64 tile (8 MFMA
// per 3 loads) was the structural cost; block count was the reason for it.
// Fix: split K across BLOCKS: grid (8,32,4) = 1024 blocks, each the SAME
// big-tile geometry that measures best (128x128 tile, per-wave 64x64,
// 16 MFMA per 4 staged loads), K=256 per block (8 steps). Double-buffered
// (32 KB LDS) -> launch_bounds(256,4): all 1024 blocks resident in ONE round,
// 4 waves/SIMD (the occupancy step that won in round 7). Epilogue: f32
// atomicAdd per output (4 contributions/element; k-group 0 folds in bias);
// d_out pre-zeroed by prep z=5. fp32 add-reorder noise ~1e-6 << tolerance.
__global__ __launch_bounds__(256, 4) void gemm1_kernel(
    const bf16* __restrict__ A, const bf16* __restrict__ Bt,
    const float* __restrict__ bias, float* __restrict__ Co) {
    __shared__ bf16 sA[2][128 * 32];
    __shared__ bf16 sB[2][128 * 32];
    const int t = threadIdx.x;
    const int wave = t >> 6, lane = t & 63;
    const int quad = lane >> 4, m16 = lane & 15;
    const int wrow = (wave >> 1) * 64, wcol = (wave & 1) * 64;
    const int row0 = blockIdx.y * 128, col0 = blockIdx.x * 128;
    const int kbase = blockIdx.z * 256;
    constexpr int NK = 8;               // 8 x 32 = 256 k per block

    f32x4 acc[4][4];
#pragma unroll
    for (int i = 0; i < 4; i++)
#pragma unroll
        for (int j = 0; j < 4; j++) acc[i][j] = (f32x4){0.f, 0.f, 0.f, 0.f};

    auto stage = [&](int kk, int buf) {
#pragma unroll
        for (int i = 0; i < 2; i++) {
            int cb = i * 256 + wave * 64;
            int c  = cb + lane;
            int r  = c >> 2, kg = c & 3;
            int gk = kg ^ ((r >> 1) & 3);
            gld_lds16(A + (size_t)(row0 + r) * D_MODEL + kbase + kk * 32 + gk * 8,
                      (char*)&sA[buf][0] + cb * 16);
        }
#pragma unroll
        for (int i = 0; i < 2; i++) {
            int cb = i * 256 + wave * 64;
            int c  = cb + lane;
            int r  = c >> 2, kg = c & 3;
            int gk = kg ^ ((r >> 1) & 3);
            gld_lds16(Bt + (size_t)(col0 + r) * D_MODEL + kbase + kk * 32 + gk * 8,
                      (char*)&sB[buf][0] + cb * 16);
        }
    };

    stage(0, 0);

    const int sx = (m16 >> 1) & 3;
    for (int ks = 0; ks < NK; ++ks) {
        // own stage(ks) done -> barrier => buf ks&1 staged for all waves;
        // barrier also means everyone finished reading buf (ks+1)&1.
        asm volatile("s_waitcnt vmcnt(0)\n\ts_barrier" ::: "memory");
        if (ks + 1 < NK) stage(ks + 1, (ks + 1) & 1);

        const int cur = ks & 1;
        const int gg = (quad ^ sx) * 8;
        bf16x8 af[4], bfr[4];
#pragma unroll
        for (int mi = 0; mi < 4; mi++)
            af[mi] = *(const bf16x8*)&sA[cur][(wrow + mi * 16 + m16) * 32 + gg];
#pragma unroll
        for (int ni = 0; ni < 4; ni++)
            bfr[ni] = *(const bf16x8*)&sB[cur][(wcol + ni * 16 + m16) * 32 + gg];
#pragma unroll
        for (int mi = 0; mi < 4; mi++)
#pragma unroll
            for (int ni = 0; ni < 4; ni++)
                acc[mi][ni] = __builtin_amdgcn_mfma_f32_16x16x32_bf16(
                    af[mi], bfr[ni], acc[mi][ni], 0, 0, 0);
    }

    // epilogue: accumulate into pre-zeroed Co; k-group 0 contributes bias.
    const bool g0 = (blockIdx.z == 0);
#pragma unroll
    for (int mi = 0; mi < 4; mi++) {
        int r0 = row0 + wrow + mi * 16 + quad * 4;
#pragma unroll
        for (int ni = 0; ni < 4; ni++) {
            int col = col0 + wcol + ni * 16 + m16;
            float bb = g0 ? bias[col] : 0.f;
#pragma unroll
            for (int r = 0; r < 4; r++)
                atomicAdd(&Co[(size_t)(r0 + r) * D_MODEL + col],
                          acc[mi][ni][r] + bb);
        }
    }
}

// ======================= flash attention (causal) ============================
// One block per (head, q-tile): grid 32x32 = 1024 blocks -> 4 blocks/CU.
// Double-buffered KV staging, prefetch depth 1; head->XCD pinning via
// blockIdx.x = bh; LPT via qt = 31-blockIdx.y. Transposed scores, per-lane
// softmax in exp2 domain, in-register P via p32+p16 double swap; V-fragment
// is the conflict-tuned ds_read_b128 from XOR-swizzled Vt_s (0 conflicts).
__global__ __launch_bounds__(256, 4) void attn_kernel(
    const bf16* __restrict__ Q, const bf16* __restrict__ K,
    const bf16* __restrict__ Vt, bf16* __restrict__ ctx) {
    __shared__ bf16 Kt_s[2][64 * 64];
    __shared__ bf16 Vt_s[2][64 * 64];

    const int t = threadIdx.x, wave = t >> 6, lane = t & 63;
    const int quad = lane >> 4, m16 = lane & 15;
    const int bh = blockIdx.x;            // head -> XCD bh%8 (L2 KV locality)
    const int qt = 31 - blockIdx.y;       // big tiles first (LPT)
    const int nt = qt + 1;                // causal KV tiles (64-wide)
    const size_t base = (size_t)bh * S_LEN * DHEAD;

    // Q fragments (B-operand), kept in regs
    bf16x8 aq[2];
#pragma unroll
    for (int kst = 0; kst < 2; kst++)
        aq[kst] = *(const bf16x8*)(Q + base
            + (size_t)(qt * 64 + wave * 16 + m16) * DHEAD + kst * 32 + quad * 8);

    f32x4 o[4];
#pragma unroll
    for (int di = 0; di < 4; di++) o[di] = (f32x4){0.f, 0.f, 0.f, 0.f};
    float l_acc = 0.f;

    auto stage = [&](int j, int buf) {
#pragma unroll
        for (int i = 0; i < 2; i++) {
            int cb = i * 256 + wave * 64;
            int c  = cb + lane;
            int pos = c >> 3, g = c & 7;
            int gk = g ^ (pos & 7);
            gld_lds16(K  + base + (size_t)(j * 64 + pos) * DHEAD + gk * 8,
                      (char*)&Kt_s[buf][0] + cb * 16);
            gld_lds16(Vt + base + (size_t)pos * S_LEN + j * 64 + gk * 8,
                      (char*)&Vt_s[buf][0] + cb * 16);
        }
    };

    stage(0, 0);

    for (int j = 0; j < nt; ++j) {
        asm volatile("s_waitcnt vmcnt(0)\n\ts_barrier" ::: "memory");
        if (j + 1 < nt) stage(j + 1, (j + 1) & 1);

        const int cur = j & 1;
        const int kt0 = j * 64;

        // ---- scores S^T[kpos][q] = K @ Q^T
        f32x4 sc[4];
#pragma unroll
        for (int ni = 0; ni < 4; ni++) sc[ni] = (f32x4){0.f, 0.f, 0.f, 0.f};
        __builtin_amdgcn_s_setprio(1);
#pragma unroll
        for (int ni = 0; ni < 4; ni++) {
            int pos = ni * 16 + m16;
#pragma unroll
            for (int kst = 0; kst < 2; kst++) {
                int gg = (kst * 4 + quad) ^ (pos & 7);
                bf16x8 kf = *(const bf16x8*)&Kt_s[cur][pos * 64 + gg * 8];
                sc[ni] = __builtin_amdgcn_mfma_f32_16x16x32_bf16(
                    kf, aq[kst], sc[ni], 0, 0, 0);
            }
        }
        __builtin_amdgcn_s_setprio(0);

        // ---- causal mask: only on the diagonal tile
        if (j == qt) {
            int qg = qt * 64 + wave * 16 + m16;
#pragma unroll
            for (int ni = 0; ni < 4; ni++)
#pragma unroll
                for (int r = 0; r < 4; r++) {
                    int kp = kt0 + ni * 16 + quad * 4 + r;
                    if (kp > qg) sc[ni][r] = -1e9f;
                }
        }

        // ---- p = exp2(s); accumulate l; pack bf16 dwords in-register.
        unsigned int pd[4][2];
        {
            float ls0 = 0.f, ls1 = 0.f;
#pragma unroll
            for (int ni = 0; ni < 4; ni++) {
                float p0 = __builtin_amdgcn_exp2f(sc[ni][0]);
                float p1 = __builtin_amdgcn_exp2f(sc[ni][1]);
                float p2 = __builtin_amdgcn_exp2f(sc[ni][2]);
                float p3 = __builtin_amdgcn_exp2f(sc[ni][3]);
                union { bf16x4 h; unsigned int u[2]; } cv;
                cv.h[0] = (bf16)p0; cv.h[1] = (bf16)p1;
                cv.h[2] = (bf16)p2; cv.h[3] = (bf16)p3;
                pd[ni][0] = cv.u[0];
                pd[ni][1] = cv.u[1];
                ls0 += p0 + p1;
                ls1 += p2 + p3;
            }
            l_acc += ls0 + ls1;
        }

        // ---- O^T += (P @ V)^T, natural k order via p32+p16 double swap
#pragma unroll
        for (int kst = 0; kst < 2; kst++) {
            unsigned int x0 = pd[2 * kst][0],     y0 = pd[2 * kst][1];
            unsigned int x1 = pd[2 * kst + 1][0], y1 = pd[2 * kst + 1][1];
            asm("v_permlane32_swap_b32 %0, %1" : "+v"(x0), "+v"(x1));
            asm("v_permlane32_swap_b32 %0, %1" : "+v"(y0), "+v"(y1));
            asm("v_permlane16_swap_b32 %0, %1" : "+v"(x0), "+v"(x1));
            asm("v_permlane16_swap_b32 %0, %1" : "+v"(y0), "+v"(y1));
            union { unsigned int u[4]; bf16x8 v; } pk;
            pk.u[0] = x0; pk.u[1] = y0; pk.u[2] = x1; pk.u[3] = y1;
            bf16x8 ap = pk.v;
            __builtin_amdgcn_s_setprio(1);
#pragma unroll
            for (int di = 0; di < 4; di++) {
                int d = di * 16 + m16;
                int gg = (kst * 4 + quad) ^ (d & 7);
                bf16x8 vf = *(const bf16x8*)&Vt_s[cur][d * 64 + gg * 8];
                o[di] = __builtin_amdgcn_mfma_f32_16x16x32_bf16(
                    vf, ap, o[di], 0, 0, 0);
            }
            __builtin_amdgcn_s_setprio(0);
        }
    }

    // ---- final l reduction + normalize + write ctx [B,S,1024] bf16
    int b = bh >> 4, h = bh & 15;
    float l = l_acc;
    l += __shfl_xor(l, 16);
    l += __shfl_xor(l, 32);
    float rl = 1.0f / l;
    int s = qt * 64 + wave * 16 + m16;
#pragma unroll
    for (int di = 0; di < 4; di++) {
        bf16x4 pk;
#pragma unroll
        for (int r = 0; r < 4; r++) pk[r] = (bf16)(o[di][r] * rl);
        *(bf16x4*)(ctx + ((size_t)b * S_LEN + s) * D_MODEL
                   + h * DHEAD + di * 16 + quad * 4) = pk;
    }
}

// ================================ launch =====================================
extern "C" void kernel_launch(void* const* d_in, const int* in_sizes, int n_in,
                              void* d_out, int out_size, void* d_ws, size_t ws_size,
                              hipStream_t stream) {
    const float* x  = (const float*)d_in[0];
    const float* Wq = (const float*)d_in[1];
    const float* bq = (const float*)d_in[2];
    const float* Wk = (const float*)d_in[3];
    const float* bk = (const float*)d_in[4];
    const float* Wv = (const float*)d_in[5];
    const float* bv = (const float*)d_in[6];
    const float* Wo = (const float*)d_in[7];
    const float* bo = (const float*)d_in[8];
    float* out = (float*)d_out;

    char* ws = (char*)d_ws;
    const size_t MB = 1u << 20;
    bf16* xb  = (bf16*)(ws + 0);         // 8 MB  [4096,1024]
    bf16* Wt  = (bf16*)(ws + 8  * MB);   // 8 MB  [4][1024][1024]
    bf16* Qb  = (bf16*)(ws + 16 * MB);   // 8 MB  [B,H,S,64]  (pre-scaled by QSCALE)
    bf16* Kb  = (bf16*)(ws + 24 * MB);   // 8 MB  [B,H,S,64]
    bf16* Vtb = (bf16*)(ws + 32 * MB);   // 8 MB  [B,H,64,S]
    bf16* ctx = (bf16*)(ws + 0);         // reuse xb region (dead after QKV GEMM)

    prep_kernel<<<dim3(32, 32, 6), dim3(32, 8), 0, stream>>>(x, Wq, Wk, Wv, Wo,
                                                             xb, Wt, out);
    gemm0_kernel<<<dim3(24, 32), 256, 0, stream>>>(xb, Wt, bq, bk, bv,
                                                   Qb, Kb, Vtb);
    attn_kernel<<<dim3(32, 32), 256, 0, stream>>>(Qb, Kb, Vtb, ctx);
    gemm1_kernel<<<dim3(8, 32, 4), 256, 0, stream>>>(ctx, Wt + 3 * 1024 * 1024,
                                                     bo, out);
}

// Round 9
// 175.871 us; speedup vs baseline: 1.2791x; 1.2791x over previous
//
#include <hip/hip_runtime.h>

typedef __bf16 bf16;
typedef __bf16 bf16x8 __attribute__((ext_vector_type(8)));
typedef __bf16 bf16x4 __attribute__((ext_vector_type(4)));
typedef float  f32x4  __attribute__((ext_vector_type(4)));

#define D_MODEL 1024
#define S_LEN   2048
#define NHEAD   16
#define DHEAD   64
#define BATCH   2
#define MROWS   (BATCH * S_LEN)   // 4096

// 0.125 (1/sqrt(dhead)) * log2(e): Q pre-scaled so softmax runs in exp2 domain
#define QSCALE 0.18033688011112042f

// ---- async global->LDS, 16B per lane. lds_base must be wave-uniform; HW
// writes lane i's data at lds_base + i*16 (guide §5 caveat).
__device__ __forceinline__ void gld_lds16(const void* g, void* lds_base) {
    __builtin_amdgcn_global_load_lds(
        (const __attribute__((address_space(1))) void*)g,
        (__attribute__((address_space(3))) void*)lds_base, 16, 0, 0);
}

// ============= prep: transpose+cast 4 weights (z<4) | cast x (z==4) ==========
__global__ void prep_kernel(const float* __restrict__ x,
                            const float* __restrict__ W0, const float* __restrict__ W1,
                            const float* __restrict__ W2, const float* __restrict__ W3,
                            bf16* __restrict__ xb, bf16* __restrict__ Wt) {
    int tx = threadIdx.x, ty = threadIdx.y;   // (32, 8)
    if (blockIdx.z == 4) {
        int tid = ty * 32 + tx;
        size_t base = ((size_t)blockIdx.y * 32 + blockIdx.x) * 4096;
#pragma unroll
        for (int j = 0; j < 4; j++) {
            size_t i = base + (size_t)(j * 256 + tid) * 4;
            f32x4 v = *(const f32x4*)(x + i);
            bf16x4 o;
            o[0] = (bf16)v[0]; o[1] = (bf16)v[1]; o[2] = (bf16)v[2]; o[3] = (bf16)v[3];
            *(bf16x4*)(xb + i) = o;
        }
        return;
    }
    __shared__ float tile[32][33];
    const float* W = (blockIdx.z == 0) ? W0 : (blockIdx.z == 1) ? W1
                   : (blockIdx.z == 2) ? W2 : W3;
    int n0 = blockIdx.x * 32, k0 = blockIdx.y * 32;
#pragma unroll
    for (int j = 0; j < 4; j++)
        tile[ty + 8 * j][tx] = W[(size_t)(k0 + ty + 8 * j) * D_MODEL + n0 + tx];
    __syncthreads();
    bf16* out = Wt + (size_t)blockIdx.z * D_MODEL * D_MODEL;
#pragma unroll
    for (int j = 0; j < 4; j++)
        out[(size_t)(n0 + ty + 8 * j) * D_MODEL + k0 + tx] = (bf16)tile[tx][ty + 8 * j];
}

// ================== gemm0: QKV projections (round-6 proven) ==================
// BM=128 BN=128 BK=32, 4 waves 2x2, per-wave 64x64 (acc[4][4], 16 MFMA per 4
// staged loads). Triple-buffered, prefetch depth 2, COUNTED vmcnt(4): own
// stage(ks) complete, newest stage(ks+1) stays in flight across the barrier.
// Staging pre-swizzles the GLOBAL k-group (LDS dest linear, required by
// global_load_lds): slot kg of row r holds k-group kg ^ ((r>>1)&3); read slot
// quad ^ ((m16>>1)&3) -> per-phase bank-starts 8 values x 2 lanes = 2-way =
// free (measured 0 conflicts, round 6). Measured 44.2 us / MfmaUtil 21 (the
// 2-phase structural ceiling; round-7 BK=64/depth-1 variant regressed; round-8
// confirmed this config is the best measured for this shape).
__global__ __launch_bounds__(256, 3) void gemm0_kernel(
    const bf16* __restrict__ A, const bf16* __restrict__ Bt,
    const float* __restrict__ b0, const float* __restrict__ b1, const float* __restrict__ b2,
    bf16* __restrict__ Qo, bf16* __restrict__ Ko, bf16* __restrict__ Vto) {
    __shared__ bf16 sA[3][128 * 32];
    __shared__ bf16 sB[3][128 * 32];
    const int t = threadIdx.x;
    const int wave = t >> 6, lane = t & 63;
    const int quad = lane >> 4, m16 = lane & 15;
    const int wrow = (wave >> 1) * 64, wcol = (wave & 1) * 64;
    const int row0 = blockIdx.y * 128, col0 = blockIdx.x * 128;
    constexpr int NK = D_MODEL / 32;

    f32x4 acc[4][4];
#pragma unroll
    for (int i = 0; i < 4; i++)
#pragma unroll
        for (int j = 0; j < 4; j++) acc[i][j] = (f32x4){0.f, 0.f, 0.f, 0.f};

    auto stage = [&](int kk, int buf) {
#pragma unroll
        for (int i = 0; i < 2; i++) {
            int cb = i * 256 + wave * 64;       // wave-uniform chunk base
            int c  = cb + lane;
            int r  = c >> 2, kg = c & 3;        // tile row, LDS slot
            int gk = kg ^ ((r >> 1) & 3);       // swizzled global k-group
            gld_lds16(A + (size_t)(row0 + r) * D_MODEL + kk * 32 + gk * 8,
                      (char*)&sA[buf][0] + cb * 16);
        }
#pragma unroll
        for (int i = 0; i < 2; i++) {
            int cb = i * 256 + wave * 64;
            int c  = cb + lane;
            int r  = c >> 2, kg = c & 3;
            int gk = kg ^ ((r >> 1) & 3);
            gld_lds16(Bt + (size_t)(col0 + r) * D_MODEL + kk * 32 + gk * 8,
                      (char*)&sB[buf][0] + cb * 16);
        }
    };

    stage(0, 0);
    stage(1, 1);

    const int sx = (m16 >> 1) & 3;    // row-derived slot swizzle (wave-inv.)
    for (int ks = 0; ks < NK; ++ks) {
        if (ks + 1 < NK)
            asm volatile("s_waitcnt vmcnt(4)\n\ts_barrier" ::: "memory");
        else
            asm volatile("s_waitcnt vmcnt(0)\n\ts_barrier" ::: "memory");
        if (ks + 2 < NK) stage(ks + 2, (ks + 2) % 3);

        const int cur = ks % 3;
        const int gg = (quad ^ sx) * 8;
        bf16x8 af[4], bfr[4];
#pragma unroll
        for (int mi = 0; mi < 4; mi++)
            af[mi] = *(const bf16x8*)&sA[cur][(wrow + mi * 16 + m16) * 32 + gg];
#pragma unroll
        for (int ni = 0; ni < 4; ni++)
            bfr[ni] = *(const bf16x8*)&sB[cur][(wcol + ni * 16 + m16) * 32 + gg];
#pragma unroll
        for (int mi = 0; mi < 4; mi++)
#pragma unroll
            for (int ni = 0; ni < 4; ni++)
                acc[mi][ni] = __builtin_amdgcn_mfma_f32_16x16x32_bf16(
                    af[mi], bfr[ni], acc[mi][ni], 0, 0, 0);
    }

    // epilogue (C/D: col = lane&15, row = quad*4 + reg; m89-verified).
    int sel = col0 >> 10;   // uniform per block (1024 % 128 == 0)
    const float* bias_arr = (sel == 0) ? b0 : (sel == 1) ? b1 : b2;
#pragma unroll
    for (int mi = 0; mi < 4; mi++) {
        int s0g = row0 + wrow + mi * 16 + quad * 4;   // global M-row base
        int b = s0g >> 11, ss0 = s0g & 2047;
#pragma unroll
        for (int ni = 0; ni < 4; ni++) {
            int col = col0 + wcol + ni * 16 + m16;
            int cn = col & 1023;
            int h = cn >> 6, d = cn & 63;
            float bias = bias_arr[cn];
            if (sel < 2) {
                bf16* dst = (sel == 0) ? Qo : Ko;
                float scl = (sel == 0) ? QSCALE : 1.0f;
                size_t base = (((size_t)b * NHEAD + h) * S_LEN);
#pragma unroll
                for (int r = 0; r < 4; r++)
                    dst[(base + ss0 + r) * DHEAD + d] = (bf16)((acc[mi][ni][r] + bias) * scl);
            } else {
                bf16x4 pk;
#pragma unroll
                for (int r = 0; r < 4; r++) pk[r] = (bf16)(acc[mi][ni][r] + bias);
                *(bf16x4*)(Vto + (((size_t)b * NHEAD + h) * DHEAD + d) * S_LEN + ss0) = pk;
            }
        }
    }
}

// ======= gemm1: output proj, intra-block split-K + XCD-pinned swizzle ========
// Round-7 structure (proven 35.6 us, no atomics -- round-8's atomic split-K
// regressed to 63 us on 64 MB of RMW traffic): 512 threads, waves 0-3 (grp 0)
// k=[0,512), waves 4-7 (grp 1) k=[512,1024), triple-buffer, counted vmcnt(3);
// grp 1 parks its partial in LDS scratch, grp 0 adds + bias.
// NEW: bijective XCD-pinning swizzle. Default round-robin gives each XCD 32
// distinct A row-panels = 8 MB > 4 MB L2 -> A thrashes to HBM. Launch 512
// blocks 1-D; decode r=p%8, q=p/8, x=q%16, y=r+8*(q/16) so hardware's p%8
// round-robin puts y%8 == XCD: per XCD = 4 A-panels (1 MB) x 16 col-blocks
// + full B (2 MB) = 3 MB < 4 MB L2 -> A re-reads become L2 hits (T1).
__global__ __launch_bounds__(512, 4) void gemm1_kernel(
    const bf16* __restrict__ A, const bf16* __restrict__ Bt,
    const float* __restrict__ bias, float* __restrict__ Co) {
    __shared__ bf16 sA[3][2][128 * 32];
    __shared__ bf16 sB[3][2][64 * 32];
    const int t = threadIdx.x;
    const int wave = t >> 6, lane = t & 63;
    const int quad = lane >> 4, m16 = lane & 15;
    const int grp = wave >> 2, w4 = wave & 3;
    const int wrow = w4 * 32;
    const int p  = blockIdx.x;                    // 0..511
    const int xb = (p >> 3) & 15;                 // col-block 0..15
    const int yb = (p & 7) + 8 * (p >> 7);        // row-block 0..31, y%8 = XCD
    const int row0 = yb * 128, col0 = xb * 64;
    const int kbase = grp * 512;
    constexpr int NK = 16;              // 16 x 32 = 512 k per group

    f32x4 acc[2][4];
#pragma unroll
    for (int i = 0; i < 2; i++)
#pragma unroll
        for (int j = 0; j < 4; j++) acc[i][j] = (f32x4){0.f, 0.f, 0.f, 0.f};

    // stage K-step kk of this group's k-half into buffer buf (3 loads/lane:
    // 2 A + 1 B, uniform across all 8 waves -> uniform vmcnt).
    auto stage = [&](int kk, int buf) {
#pragma unroll
        for (int i = 0; i < 2; i++) {
            int cb = i * 256 + w4 * 64;
            int c  = cb + lane;
            int r  = c >> 2, kg = c & 3;
            int gk = kg ^ ((r >> 1) & 3);
            gld_lds16(A + (size_t)(row0 + r) * D_MODEL + kbase + kk * 32 + gk * 8,
                      (char*)&sA[buf][grp][0] + cb * 16);
        }
        {
            int cb = w4 * 64;
            int c  = cb + lane;
            int r  = c >> 2, kg = c & 3;
            int gk = kg ^ ((r >> 1) & 3);
            gld_lds16(Bt + (size_t)(col0 + r) * D_MODEL + kbase + kk * 32 + gk * 8,
                      (char*)&sB[buf][grp][0] + cb * 16);
        }
    };

    stage(0, 0);
    stage(1, 1);

    const int sx = (m16 >> 1) & 3;
    for (int ks = 0; ks < NK; ++ks) {
        if (ks + 1 < NK)
            asm volatile("s_waitcnt vmcnt(3)\n\ts_barrier" ::: "memory");
        else
            asm volatile("s_waitcnt vmcnt(0)\n\ts_barrier" ::: "memory");
        if (ks + 2 < NK) stage(ks + 2, (ks + 2) % 3);

        const int cur = ks % 3;
        const int gg = (quad ^ sx) * 8;
        bf16x8 af[2], bfr[4];
#pragma unroll
        for (int mi = 0; mi < 2; mi++)
            af[mi] = *(const bf16x8*)&sA[cur][grp][(wrow + mi * 16 + m16) * 32 + gg];
#pragma unroll
        for (int ni = 0; ni < 4; ni++)
            bfr[ni] = *(const bf16x8*)&sB[cur][grp][(ni * 16 + m16) * 32 + gg];
#pragma unroll
        for (int mi = 0; mi < 2; mi++)
#pragma unroll
            for (int ni = 0; ni < 4; ni++)
                acc[mi][ni] = __builtin_amdgcn_mfma_f32_16x16x32_bf16(
                    af[mi], bfr[ni], acc[mi][ni], 0, 0, 0);
    }

    // ---- cross-group reduce via LDS scratch (re-uses staging buffers; all
    // LDS reads of the K-loop completed before the first barrier below).
    __syncthreads();
    float* scr = (float*)&sA[0][0][0];   // 128 x 66 f32 = 33.8 KB < 48 KB
    if (grp == 1) {
#pragma unroll
        for (int mi = 0; mi < 2; mi++)
#pragma unroll
            for (int ni = 0; ni < 4; ni++)
#pragma unroll
                for (int r = 0; r < 4; r++)
                    scr[(wrow + mi * 16 + quad * 4 + r) * 66 + ni * 16 + m16] =
                        acc[mi][ni][r];
    }
    __syncthreads();
    if (grp == 0) {
#pragma unroll
        for (int mi = 0; mi < 2; mi++)
#pragma unroll
            for (int ni = 0; ni < 4; ni++) {
                int col = col0 + ni * 16 + m16;
                float bb = bias[col];
#pragma unroll
                for (int r = 0; r < 4; r++) {
                    int row = wrow + mi * 16 + quad * 4 + r;
                    Co[(size_t)(row0 + row) * D_MODEL + col] =
                        acc[mi][ni][r] + scr[row * 66 + ni * 16 + m16] + bb;
                }
            }
    }
}

// ======================= flash attention (causal) ============================
// One block per (head, q-tile): grid 32x32 = 1024 blocks -> 4 blocks/CU.
// Double-buffered KV staging, prefetch depth 1; head->XCD pinning via
// blockIdx.x = bh; LPT via qt = 31-blockIdx.y. Transposed scores, per-lane
// softmax in exp2 domain, in-register P via p32+p16 double swap; V-fragment
// is the conflict-tuned ds_read_b128 from XOR-swizzled Vt_s (0 conflicts).
__global__ __launch_bounds__(256, 4) void attn_kernel(
    const bf16* __restrict__ Q, const bf16* __restrict__ K,
    const bf16* __restrict__ Vt, bf16* __restrict__ ctx) {
    __shared__ bf16 Kt_s[2][64 * 64];
    __shared__ bf16 Vt_s[2][64 * 64];

    const int t = threadIdx.x, wave = t >> 6, lane = t & 63;
    const int quad = lane >> 4, m16 = lane & 15;
    const int bh = blockIdx.x;            // head -> XCD bh%8 (L2 KV locality)
    const int qt = 31 - blockIdx.y;       // big tiles first (LPT)
    const int nt = qt + 1;                // causal KV tiles (64-wide)
    const size_t base = (size_t)bh * S_LEN * DHEAD;

    // Q fragments (B-operand), kept in regs
    bf16x8 aq[2];
#pragma unroll
    for (int kst = 0; kst < 2; kst++)
        aq[kst] = *(const bf16x8*)(Q + base
            + (size_t)(qt * 64 + wave * 16 + m16) * DHEAD + kst * 32 + quad * 8);

    f32x4 o[4];
#pragma unroll
    for (int di = 0; di < 4; di++) o[di] = (f32x4){0.f, 0.f, 0.f, 0.f};
    float l_acc = 0.f;

    auto stage = [&](int j, int buf) {
#pragma unroll
        for (int i = 0; i < 2; i++) {
            int cb = i * 256 + wave * 64;
            int c  = cb + lane;
            int pos = c >> 3, g = c & 7;
            int gk = g ^ (pos & 7);
            gld_lds16(K  + base + (size_t)(j * 64 + pos) * DHEAD + gk * 8,
                      (char*)&Kt_s[buf][0] + cb * 16);
            gld_lds16(Vt + base + (size_t)pos * S_LEN + j * 64 + gk * 8,
                      (char*)&Vt_s[buf][0] + cb * 16);
        }
    };

    stage(0, 0);

    for (int j = 0; j < nt; ++j) {
        asm volatile("s_waitcnt vmcnt(0)\n\ts_barrier" ::: "memory");
        if (j + 1 < nt) stage(j + 1, (j + 1) & 1);

        const int cur = j & 1;
        const int kt0 = j * 64;

        // ---- scores S^T[kpos][q] = K @ Q^T
        f32x4 sc[4];
#pragma unroll
        for (int ni = 0; ni < 4; ni++) sc[ni] = (f32x4){0.f, 0.f, 0.f, 0.f};
        __builtin_amdgcn_s_setprio(1);
#pragma unroll
        for (int ni = 0; ni < 4; ni++) {
            int pos = ni * 16 + m16;
#pragma unroll
            for (int kst = 0; kst < 2; kst++) {
                int gg = (kst * 4 + quad) ^ (pos & 7);
                bf16x8 kf = *(const bf16x8*)&Kt_s[cur][pos * 64 + gg * 8];
                sc[ni] = __builtin_amdgcn_mfma_f32_16x16x32_bf16(
                    kf, aq[kst], sc[ni], 0, 0, 0);
            }
        }
        __builtin_amdgcn_s_setprio(0);

        // ---- causal mask: only on the diagonal tile
        if (j == qt) {
            int qg = qt * 64 + wave * 16 + m16;
#pragma unroll
            for (int ni = 0; ni < 4; ni++)
#pragma unroll
                for (int r = 0; r < 4; r++) {
                    int kp = kt0 + ni * 16 + quad * 4 + r;
                    if (kp > qg) sc[ni][r] = -1e9f;
                }
        }

        // ---- p = exp2(s); accumulate l; pack bf16 dwords in-register.
        unsigned int pd[4][2];
        {
            float ls0 = 0.f, ls1 = 0.f;
#pragma unroll
            for (int ni = 0; ni < 4; ni++) {
                float p0 = __builtin_amdgcn_exp2f(sc[ni][0]);
                float p1 = __builtin_amdgcn_exp2f(sc[ni][1]);
                float p2 = __builtin_amdgcn_exp2f(sc[ni][2]);
                float p3 = __builtin_amdgcn_exp2f(sc[ni][3]);
                union { bf16x4 h; unsigned int u[2]; } cv;
                cv.h[0] = (bf16)p0; cv.h[1] = (bf16)p1;
                cv.h[2] = (bf16)p2; cv.h[3] = (bf16)p3;
                pd[ni][0] = cv.u[0];
                pd[ni][1] = cv.u[1];
                ls0 += p0 + p1;
                ls1 += p2 + p3;
            }
            l_acc += ls0 + ls1;
        }

        // ---- O^T += (P @ V)^T, natural k order via p32+p16 double swap
#pragma unroll
        for (int kst = 0; kst < 2; kst++) {
            unsigned int x0 = pd[2 * kst][0],     y0 = pd[2 * kst][1];
            unsigned int x1 = pd[2 * kst + 1][0], y1 = pd[2 * kst + 1][1];
            asm("v_permlane32_swap_b32 %0, %1" : "+v"(x0), "+v"(x1));
            asm("v_permlane32_swap_b32 %0, %1" : "+v"(y0), "+v"(y1));
            asm("v_permlane16_swap_b32 %0, %1" : "+v"(x0), "+v"(x1));
            asm("v_permlane16_swap_b32 %0, %1" : "+v"(y0), "+v"(y1));
            union { unsigned int u[4]; bf16x8 v; } pk;
            pk.u[0] = x0; pk.u[1] = y0; pk.u[2] = x1; pk.u[3] = y1;
            bf16x8 ap = pk.v;
            __builtin_amdgcn_s_setprio(1);
#pragma unroll
            for (int di = 0; di < 4; di++) {
                int d = di * 16 + m16;
                int gg = (kst * 4 + quad) ^ (d & 7);
                bf16x8 vf = *(const bf16x8*)&Vt_s[cur][d * 64 + gg * 8];
                o[di] = __builtin_amdgcn_mfma_f32_16x16x32_bf16(
                    vf, ap, o[di], 0, 0, 0);
            }
            __builtin_amdgcn_s_setprio(0);
        }
    }

    // ---- final l reduction + normalize + write ctx [B,S,1024] bf16
    int b = bh >> 4, h = bh & 15;
    float l = l_acc;
    l += __shfl_xor(l, 16);
    l += __shfl_xor(l, 32);
    float rl = 1.0f / l;
    int s = qt * 64 + wave * 16 + m16;
#pragma unroll
    for (int di = 0; di < 4; di++) {
        bf16x4 pk;
#pragma unroll
        for (int r = 0; r < 4; r++) pk[r] = (bf16)(o[di][r] * rl);
        *(bf16x4*)(ctx + ((size_t)b * S_LEN + s) * D_MODEL
                   + h * DHEAD + di * 16 + quad * 4) = pk;
    }
}

// ================================ launch =====================================
extern "C" void kernel_launch(void* const* d_in, const int* in_sizes, int n_in,
                              void* d_out, int out_size, void* d_ws, size_t ws_size,
                              hipStream_t stream) {
    const float* x  = (const float*)d_in[0];
    const float* Wq = (const float*)d_in[1];
    const float* bq = (const float*)d_in[2];
    const float* Wk = (const float*)d_in[3];
    const float* bk = (const float*)d_in[4];
    const float* Wv = (const float*)d_in[5];
    const float* bv = (const float*)d_in[6];
    const float* Wo = (const float*)d_in[7];
    const float* bo = (const float*)d_in[8];
    float* out = (float*)d_out;

    char* ws = (char*)d_ws;
    const size_t MB = 1u << 20;
    bf16* xb  = (bf16*)(ws + 0);         // 8 MB  [4096,1024]
    bf16* Wt  = (bf16*)(ws + 8  * MB);   // 8 MB  [4][1024][1024]
    bf16* Qb  = (bf16*)(ws + 16 * MB);   // 8 MB  [B,H,S,64]  (pre-scaled by QSCALE)
    bf16* Kb  = (bf16*)(ws + 24 * MB);   // 8 MB  [B,H,S,64]
    bf16* Vtb = (bf16*)(ws + 32 * MB);   // 8 MB  [B,H,64,S]
    bf16* ctx = (bf16*)(ws + 0);         // reuse xb region (dead after QKV GEMM)

    prep_kernel<<<dim3(32, 32, 5), dim3(32, 8), 0, stream>>>(x, Wq, Wk, Wv, Wo,
                                                             xb, Wt);
    gemm0_kernel<<<dim3(24, 32), 256, 0, stream>>>(xb, Wt, bq, bk, bv,
                                                   Qb, Kb, Vtb);
    attn_kernel<<<dim3(32, 32), 256, 0, stream>>>(Qb, Kb, Vtb, ctx);
    gemm1_kernel<<<dim3(512), 512, 0, stream>>>(ctx, Wt + 3 * 1024 * 1024,
                                                bo, out);
}

// Round 10
// 174.706 us; speedup vs baseline: 1.2876x; 1.0067x over previous
//
#include <hip/hip_runtime.h>

typedef __bf16 bf16;
typedef __bf16 bf16x8 __attribute__((ext_vector_type(8)));
typedef __bf16 bf16x4 __attribute__((ext_vector_type(4)));
typedef float  f32x4  __attribute__((ext_vector_type(4)));

#define D_MODEL 1024
#define S_LEN   2048
#define NHEAD   16
#define DHEAD   64
#define BATCH   2
#define MROWS   (BATCH * S_LEN)   // 4096

// 0.125 (1/sqrt(dhead)) * log2(e): Q pre-scaled so softmax runs in exp2 domain
#define QSCALE 0.18033688011112042f

// ---- async global->LDS, 16B per lane. lds_base must be wave-uniform; HW
// writes lane i's data at lds_base + i*16 (guide §5 caveat).
__device__ __forceinline__ void gld_lds16(const void* g, void* lds_base) {
    __builtin_amdgcn_global_load_lds(
        (const __attribute__((address_space(1))) void*)g,
        (__attribute__((address_space(3))) void*)lds_base, 16, 0, 0);
}

// ============= prep: transpose+cast 4 weights (z<4) | cast x (z==4) ==========
__global__ void prep_kernel(const float* __restrict__ x,
                            const float* __restrict__ W0, const float* __restrict__ W1,
                            const float* __restrict__ W2, const float* __restrict__ W3,
                            bf16* __restrict__ xb, bf16* __restrict__ Wt) {
    int tx = threadIdx.x, ty = threadIdx.y;   // (32, 8)
    if (blockIdx.z == 4) {
        int tid = ty * 32 + tx;
        size_t base = ((size_t)blockIdx.y * 32 + blockIdx.x) * 4096;
#pragma unroll
        for (int j = 0; j < 4; j++) {
            size_t i = base + (size_t)(j * 256 + tid) * 4;
            f32x4 v = *(const f32x4*)(x + i);
            bf16x4 o;
            o[0] = (bf16)v[0]; o[1] = (bf16)v[1]; o[2] = (bf16)v[2]; o[3] = (bf16)v[3];
            *(bf16x4*)(xb + i) = o;
        }
        return;
    }
    __shared__ float tile[32][33];
    const float* W = (blockIdx.z == 0) ? W0 : (blockIdx.z == 1) ? W1
                   : (blockIdx.z == 2) ? W2 : W3;
    int n0 = blockIdx.x * 32, k0 = blockIdx.y * 32;
#pragma unroll
    for (int j = 0; j < 4; j++)
        tile[ty + 8 * j][tx] = W[(size_t)(k0 + ty + 8 * j) * D_MODEL + n0 + tx];
    __syncthreads();
    bf16* out = Wt + (size_t)blockIdx.z * D_MODEL * D_MODEL;
#pragma unroll
    for (int j = 0; j < 4; j++)
        out[(size_t)(n0 + ty + 8 * j) * D_MODEL + k0 + tx] = (bf16)tile[tx][ty + 8 * j];
}

// ================== gemm0: QKV projections (round-6 proven) ==================
// BM=128 BN=128 BK=32, 4 waves 2x2, per-wave 64x64 (acc[4][4], 16 MFMA per 4
// staged loads). Triple-buffered, prefetch depth 2, COUNTED vmcnt(4): own
// stage(ks) complete, newest stage(ks+1) stays in flight across the barrier.
// Staging pre-swizzles the GLOBAL k-group (LDS dest linear, required by
// global_load_lds): slot kg of row r holds k-group kg ^ ((r>>1)&3); read slot
// quad ^ ((m16>>1)&3) -> per-phase bank-starts 8 values x 2 lanes = 2-way =
// free (measured 0 conflicts). Measured 44.2/40 us, MfmaUtil ~21 (the 2-phase
// structural ceiling for this discipline).
// NEW (round 10): 2-D XCD-chunked block mapping. Default p%8 round-robin
// gives each XCD A-panels from all 32 y -> 8 MB working set > 4 MB L2 ->
// re-reads (A x24, B x32) go to L3/HBM: FETCH 35.9 MB vs ~14 ideal. Remap
// 768 = 8 XCDs x 96: XCD r owns rectangle x in [12(r&1), +12), y in
// [8(r>>1), +8), x-major within -> 12 consecutive same-XCD blocks share one
// A-panel (256 KB) while the 12 B-panels (3 MB) stay L2-resident. Bijective
// (768 % 8 == 0, idx in [0,96) exact).
__global__ __launch_bounds__(256, 3) void gemm0_kernel(
    const bf16* __restrict__ A, const bf16* __restrict__ Bt,
    const float* __restrict__ b0, const float* __restrict__ b1, const float* __restrict__ b2,
    bf16* __restrict__ Qo, bf16* __restrict__ Ko, bf16* __restrict__ Vto) {
    __shared__ bf16 sA[3][128 * 32];
    __shared__ bf16 sB[3][128 * 32];
    const int t = threadIdx.x;
    const int wave = t >> 6, lane = t & 63;
    const int quad = lane >> 4, m16 = lane & 15;
    const int wrow = (wave >> 1) * 64, wcol = (wave & 1) * 64;
    // ---- XCD-chunked decode: p -> (xb2, yb2)
    const int p   = blockIdx.x;            // 0..767
    const int r8  = p & 7;                 // XCD (hardware round-robins p%8)
    const int idx = p >> 3;                // 0..95 within this XCD's rectangle
    const int xl  = idx % 12, yl = idx / 12;
    const int xb2 = (r8 & 1) * 12 + xl;    // 0..23 (col-block)
    const int yb2 = (r8 >> 1) * 8 + yl;    // 0..31 (row-block)
    const int row0 = yb2 * 128, col0 = xb2 * 128;
    constexpr int NK = D_MODEL / 32;

    f32x4 acc[4][4];
#pragma unroll
    for (int i = 0; i < 4; i++)
#pragma unroll
        for (int j = 0; j < 4; j++) acc[i][j] = (f32x4){0.f, 0.f, 0.f, 0.f};

    auto stage = [&](int kk, int buf) {
#pragma unroll
        for (int i = 0; i < 2; i++) {
            int cb = i * 256 + wave * 64;       // wave-uniform chunk base
            int c  = cb + lane;
            int r  = c >> 2, kg = c & 3;        // tile row, LDS slot
            int gk = kg ^ ((r >> 1) & 3);       // swizzled global k-group
            gld_lds16(A + (size_t)(row0 + r) * D_MODEL + kk * 32 + gk * 8,
                      (char*)&sA[buf][0] + cb * 16);
        }
#pragma unroll
        for (int i = 0; i < 2; i++) {
            int cb = i * 256 + wave * 64;
            int c  = cb + lane;
            int r  = c >> 2, kg = c & 3;
            int gk = kg ^ ((r >> 1) & 3);
            gld_lds16(Bt + (size_t)(col0 + r) * D_MODEL + kk * 32 + gk * 8,
                      (char*)&sB[buf][0] + cb * 16);
        }
    };

    stage(0, 0);
    stage(1, 1);

    const int sx = (m16 >> 1) & 3;    // row-derived slot swizzle (wave-inv.)
    for (int ks = 0; ks < NK; ++ks) {
        if (ks + 1 < NK)
            asm volatile("s_waitcnt vmcnt(4)\n\ts_barrier" ::: "memory");
        else
            asm volatile("s_waitcnt vmcnt(0)\n\ts_barrier" ::: "memory");
        if (ks + 2 < NK) stage(ks + 2, (ks + 2) % 3);

        const int cur = ks % 3;
        const int gg = (quad ^ sx) * 8;
        bf16x8 af[4], bfr[4];
#pragma unroll
        for (int mi = 0; mi < 4; mi++)
            af[mi] = *(const bf16x8*)&sA[cur][(wrow + mi * 16 + m16) * 32 + gg];
#pragma unroll
        for (int ni = 0; ni < 4; ni++)
            bfr[ni] = *(const bf16x8*)&sB[cur][(wcol + ni * 16 + m16) * 32 + gg];
#pragma unroll
        for (int mi = 0; mi < 4; mi++)
#pragma unroll
            for (int ni = 0; ni < 4; ni++)
                acc[mi][ni] = __builtin_amdgcn_mfma_f32_16x16x32_bf16(
                    af[mi], bfr[ni], acc[mi][ni], 0, 0, 0);
    }

    // epilogue (C/D: col = lane&15, row = quad*4 + reg; m89-verified).
    int sel = col0 >> 10;   // uniform per block (1024 % 128 == 0)
    const float* bias_arr = (sel == 0) ? b0 : (sel == 1) ? b1 : b2;
#pragma unroll
    for (int mi = 0; mi < 4; mi++) {
        int s0g = row0 + wrow + mi * 16 + quad * 4;   // global M-row base
        int b = s0g >> 11, ss0 = s0g & 2047;
#pragma unroll
        for (int ni = 0; ni < 4; ni++) {
            int col = col0 + wcol + ni * 16 + m16;
            int cn = col & 1023;
            int h = cn >> 6, d = cn & 63;
            float bias = bias_arr[cn];
            if (sel < 2) {
                bf16* dst = (sel == 0) ? Qo : Ko;
                float scl = (sel == 0) ? QSCALE : 1.0f;
                size_t base = (((size_t)b * NHEAD + h) * S_LEN);
#pragma unroll
                for (int r = 0; r < 4; r++)
                    dst[(base + ss0 + r) * DHEAD + d] = (bf16)((acc[mi][ni][r] + bias) * scl);
            } else {
                bf16x4 pk;
#pragma unroll
                for (int r = 0; r < 4; r++) pk[r] = (bf16)(acc[mi][ni][r] + bias);
                *(bf16x4*)(Vto + (((size_t)b * NHEAD + h) * DHEAD + d) * S_LEN + ss0) = pk;
            }
        }
    }
}

// ======= gemm1: output proj, intra-block split-K + XCD-pinned swizzle ========
// Round-7 structure (proven 35.6 us, no atomics -- round-8's atomic split-K
// regressed to 63 us on 64 MB of RMW traffic): 512 threads, waves 0-3 (grp 0)
// k=[0,512), waves 4-7 (grp 1) k=[512,1024), triple-buffer, counted vmcnt(3);
// grp 1 parks its partial in LDS scratch, grp 0 adds + bias.
// Bijective XCD-pinning swizzle (round 9, landed: gemm1 dropped out of top-5):
// p%8 = y%8 = XCD; per XCD = 4 A-panels (1 MB) + full B (2 MB) < 4 MB L2.
__global__ __launch_bounds__(512, 4) void gemm1_kernel(
    const bf16* __restrict__ A, const bf16* __restrict__ Bt,
    const float* __restrict__ bias, float* __restrict__ Co) {
    __shared__ bf16 sA[3][2][128 * 32];
    __shared__ bf16 sB[3][2][64 * 32];
    const int t = threadIdx.x;
    const int wave = t >> 6, lane = t & 63;
    const int quad = lane >> 4, m16 = lane & 15;
    const int grp = wave >> 2, w4 = wave & 3;
    const int wrow = w4 * 32;
    const int p  = blockIdx.x;                    // 0..511
    const int xb = (p >> 3) & 15;                 // col-block 0..15
    const int yb = (p & 7) + 8 * (p >> 7);        // row-block 0..31, y%8 = XCD
    const int row0 = yb * 128, col0 = xb * 64;
    const int kbase = grp * 512;
    constexpr int NK = 16;              // 16 x 32 = 512 k per group

    f32x4 acc[2][4];
#pragma unroll
    for (int i = 0; i < 2; i++)
#pragma unroll
        for (int j = 0; j < 4; j++) acc[i][j] = (f32x4){0.f, 0.f, 0.f, 0.f};

    // stage K-step kk of this group's k-half into buffer buf (3 loads/lane:
    // 2 A + 1 B, uniform across all 8 waves -> uniform vmcnt).
    auto stage = [&](int kk, int buf) {
#pragma unroll
        for (int i = 0; i < 2; i++) {
            int cb = i * 256 + w4 * 64;
            int c  = cb + lane;
            int r  = c >> 2, kg = c & 3;
            int gk = kg ^ ((r >> 1) & 3);
            gld_lds16(A + (size_t)(row0 + r) * D_MODEL + kbase + kk * 32 + gk * 8,
                      (char*)&sA[buf][grp][0] + cb * 16);
        }
        {
            int cb = w4 * 64;
            int c  = cb + lane;
            int r  = c >> 2, kg = c & 3;
            int gk = kg ^ ((r >> 1) & 3);
            gld_lds16(Bt + (size_t)(col0 + r) * D_MODEL + kbase + kk * 32 + gk * 8,
                      (char*)&sB[buf][grp][0] + cb * 16);
        }
    };

    stage(0, 0);
    stage(1, 1);

    const int sx = (m16 >> 1) & 3;
    for (int ks = 0; ks < NK; ++ks) {
        if (ks + 1 < NK)
            asm volatile("s_waitcnt vmcnt(3)\n\ts_barrier" ::: "memory");
        else
            asm volatile("s_waitcnt vmcnt(0)\n\ts_barrier" ::: "memory");
        if (ks + 2 < NK) stage(ks + 2, (ks + 2) % 3);

        const int cur = ks % 3;
        const int gg = (quad ^ sx) * 8;
        bf16x8 af[2], bfr[4];
#pragma unroll
        for (int mi = 0; mi < 2; mi++)
            af[mi] = *(const bf16x8*)&sA[cur][grp][(wrow + mi * 16 + m16) * 32 + gg];
#pragma unroll
        for (int ni = 0; ni < 4; ni++)
            bfr[ni] = *(const bf16x8*)&sB[cur][grp][(ni * 16 + m16) * 32 + gg];
#pragma unroll
        for (int mi = 0; mi < 2; mi++)
#pragma unroll
            for (int ni = 0; ni < 4; ni++)
                acc[mi][ni] = __builtin_amdgcn_mfma_f32_16x16x32_bf16(
                    af[mi], bfr[ni], acc[mi][ni], 0, 0, 0);
    }

    // ---- cross-group reduce via LDS scratch (re-uses staging buffers; all
    // LDS reads of the K-loop completed before the first barrier below).
    __syncthreads();
    float* scr = (float*)&sA[0][0][0];   // 128 x 66 f32 = 33.8 KB < 48 KB
    if (grp == 1) {
#pragma unroll
        for (int mi = 0; mi < 2; mi++)
#pragma unroll
            for (int ni = 0; ni < 4; ni++)
#pragma unroll
                for (int r = 0; r < 4; r++)
                    scr[(wrow + mi * 16 + quad * 4 + r) * 66 + ni * 16 + m16] =
                        acc[mi][ni][r];
    }
    __syncthreads();
    if (grp == 0) {
#pragma unroll
        for (int mi = 0; mi < 2; mi++)
#pragma unroll
            for (int ni = 0; ni < 4; ni++) {
                int col = col0 + ni * 16 + m16;
                float bb = bias[col];
#pragma unroll
                for (int r = 0; r < 4; r++) {
                    int row = wrow + mi * 16 + quad * 4 + r;
                    Co[(size_t)(row0 + row) * D_MODEL + col] =
                        acc[mi][ni][r] + scr[row * 66 + ni * 16 + m16] + bb;
                }
            }
    }
}

// ======================= flash attention (causal) ============================
// One block per (head, q-tile): grid 32x32 = 1024 blocks -> 4 blocks/CU.
// Double-buffered KV staging, prefetch depth 1; head->XCD pinning via
// blockIdx.x = bh; LPT via qt = 31-blockIdx.y. Transposed scores, per-lane
// softmax in exp2 domain, in-register P via p32+p16 double swap; V-fragment
// is the conflict-tuned ds_read_b128 from XOR-swizzled Vt_s (0 conflicts).
__global__ __launch_bounds__(256, 4) void attn_kernel(
    const bf16* __restrict__ Q, const bf16* __restrict__ K,
    const bf16* __restrict__ Vt, bf16* __restrict__ ctx) {
    __shared__ bf16 Kt_s[2][64 * 64];
    __shared__ bf16 Vt_s[2][64 * 64];

    const int t = threadIdx.x, wave = t >> 6, lane = t & 63;
    const int quad = lane >> 4, m16 = lane & 15;
    const int bh = blockIdx.x;            // head -> XCD bh%8 (L2 KV locality)
    const int qt = 31 - blockIdx.y;       // big tiles first (LPT)
    const int nt = qt + 1;                // causal KV tiles (64-wide)
    const size_t base = (size_t)bh * S_LEN * DHEAD;

    // Q fragments (B-operand), kept in regs
    bf16x8 aq[2];
#pragma unroll
    for (int kst = 0; kst < 2; kst++)
        aq[kst] = *(const bf16x8*)(Q + base
            + (size_t)(qt * 64 + wave * 16 + m16) * DHEAD + kst * 32 + quad * 8);

    f32x4 o[4];
#pragma unroll
    for (int di = 0; di < 4; di++) o[di] = (f32x4){0.f, 0.f, 0.f, 0.f};
    float l_acc = 0.f;

    auto stage = [&](int j, int buf) {
#pragma unroll
        for (int i = 0; i < 2; i++) {
            int cb = i * 256 + wave * 64;
            int c  = cb + lane;
            int pos = c >> 3, g = c & 7;
            int gk = g ^ (pos & 7);
            gld_lds16(K  + base + (size_t)(j * 64 + pos) * DHEAD + gk * 8,
                      (char*)&Kt_s[buf][0] + cb * 16);
            gld_lds16(Vt + base + (size_t)pos * S_LEN + j * 64 + gk * 8,
                      (char*)&Vt_s[buf][0] + cb * 16);
        }
    };

    stage(0, 0);

    for (int j = 0; j < nt; ++j) {
        asm volatile("s_waitcnt vmcnt(0)\n\ts_barrier" ::: "memory");
        if (j + 1 < nt) stage(j + 1, (j + 1) & 1);

        const int cur = j & 1;
        const int kt0 = j * 64;

        // ---- scores S^T[kpos][q] = K @ Q^T
        f32x4 sc[4];
#pragma unroll
        for (int ni = 0; ni < 4; ni++) sc[ni] = (f32x4){0.f, 0.f, 0.f, 0.f};
        __builtin_amdgcn_s_setprio(1);
#pragma unroll
        for (int ni = 0; ni < 4; ni++) {
            int pos = ni * 16 + m16;
#pragma unroll
            for (int kst = 0; kst < 2; kst++) {
                int gg = (kst * 4 + quad) ^ (pos & 7);
                bf16x8 kf = *(const bf16x8*)&Kt_s[cur][pos * 64 + gg * 8];
                sc[ni] = __builtin_amdgcn_mfma_f32_16x16x32_bf16(
                    kf, aq[kst], sc[ni], 0, 0, 0);
            }
        }
        __builtin_amdgcn_s_setprio(0);

        // ---- causal mask: only on the diagonal tile
        if (j == qt) {
            int qg = qt * 64 + wave * 16 + m16;
#pragma unroll
            for (int ni = 0; ni < 4; ni++)
#pragma unroll
                for (int r = 0; r < 4; r++) {
                    int kp = kt0 + ni * 16 + quad * 4 + r;
                    if (kp > qg) sc[ni][r] = -1e9f;
                }
        }

        // ---- p = exp2(s); accumulate l; pack bf16 dwords in-register.
        unsigned int pd[4][2];
        {
            float ls0 = 0.f, ls1 = 0.f;
#pragma unroll
            for (int ni = 0; ni < 4; ni++) {
                float p0 = __builtin_amdgcn_exp2f(sc[ni][0]);
                float p1 = __builtin_amdgcn_exp2f(sc[ni][1]);
                float p2 = __builtin_amdgcn_exp2f(sc[ni][2]);
                float p3 = __builtin_amdgcn_exp2f(sc[ni][3]);
                union { bf16x4 h; unsigned int u[2]; } cv;
                cv.h[0] = (bf16)p0; cv.h[1] = (bf16)p1;
                cv.h[2] = (bf16)p2; cv.h[3] = (bf16)p3;
                pd[ni][0] = cv.u[0];
                pd[ni][1] = cv.u[1];
                ls0 += p0 + p1;
                ls1 += p2 + p3;
            }
            l_acc += ls0 + ls1;
        }

        // ---- O^T += (P @ V)^T, natural k order via p32+p16 double swap
#pragma unroll
        for (int kst = 0; kst < 2; kst++) {
            unsigned int x0 = pd[2 * kst][0],     y0 = pd[2 * kst][1];
            unsigned int x1 = pd[2 * kst + 1][0], y1 = pd[2 * kst + 1][1];
            asm("v_permlane32_swap_b32 %0, %1" : "+v"(x0), "+v"(x1));
            asm("v_permlane32_swap_b32 %0, %1" : "+v"(y0), "+v"(y1));
            asm("v_permlane16_swap_b32 %0, %1" : "+v"(x0), "+v"(x1));
            asm("v_permlane16_swap_b32 %0, %1" : "+v"(y0), "+v"(y1));
            union { unsigned int u[4]; bf16x8 v; } pk;
            pk.u[0] = x0; pk.u[1] = y0; pk.u[2] = x1; pk.u[3] = y1;
            bf16x8 ap = pk.v;
            __builtin_amdgcn_s_setprio(1);
#pragma unroll
            for (int di = 0; di < 4; di++) {
                int d = di * 16 + m16;
                int gg = (kst * 4 + quad) ^ (d & 7);
                bf16x8 vf = *(const bf16x8*)&Vt_s[cur][d * 64 + gg * 8];
                o[di] = __builtin_amdgcn_mfma_f32_16x16x32_bf16(
                    vf, ap, o[di], 0, 0, 0);
            }
            __builtin_amdgcn_s_setprio(0);
        }
    }

    // ---- final l reduction + normalize + write ctx [B,S,1024] bf16
    int b = bh >> 4, h = bh & 15;
    float l = l_acc;
    l += __shfl_xor(l, 16);
    l += __shfl_xor(l, 32);
    float rl = 1.0f / l;
    int s = qt * 64 + wave * 16 + m16;
#pragma unroll
    for (int di = 0; di < 4; di++) {
        bf16x4 pk;
#pragma unroll
        for (int r = 0; r < 4; r++) pk[r] = (bf16)(o[di][r] * rl);
        *(bf16x4*)(ctx + ((size_t)b * S_LEN + s) * D_MODEL
                   + h * DHEAD + di * 16 + quad * 4) = pk;
    }
}

// ================================ launch =====================================
extern "C" void kernel_launch(void* const* d_in, const int* in_sizes, int n_in,
                              void* d_out, int out_size, void* d_ws, size_t ws_size,
                              hipStream_t stream) {
    const float* x  = (const float*)d_in[0];
    const float* Wq = (const float*)d_in[1];
    const float* bq = (const float*)d_in[2];
    const float* Wk = (const float*)d_in[3];
    const float* bk = (const float*)d_in[4];
    const float* Wv = (const float*)d_in[5];
    const float* bv = (const float*)d_in[6];
    const float* Wo = (const float*)d_in[7];
    const float* bo = (const float*)d_in[8];
    float* out = (float*)d_out;

    char* ws = (char*)d_ws;
    const size_t MB = 1u << 20;
    bf16* xb  = (bf16*)(ws + 0);         // 8 MB  [4096,1024]
    bf16* Wt  = (bf16*)(ws + 8  * MB);   // 8 MB  [4][1024][1024]
    bf16* Qb  = (bf16*)(ws + 16 * MB);   // 8 MB  [B,H,S,64]  (pre-scaled by QSCALE)
    bf16* Kb  = (bf16*)(ws + 24 * MB);   // 8 MB  [B,H,S,64]
    bf16* Vtb = (bf16*)(ws + 32 * MB);   // 8 MB  [B,H,64,S]
    bf16* ctx = (bf16*)(ws + 0);         // reuse xb region (dead after QKV GEMM)

    prep_kernel<<<dim3(32, 32, 5), dim3(32, 8), 0, stream>>>(x, Wq, Wk, Wv, Wo,
                                                             xb, Wt);
    gemm0_kernel<<<dim3(768), 256, 0, stream>>>(xb, Wt, bq, bk, bv,
                                                Qb, Kb, Vtb);
    attn_kernel<<<dim3(32, 32), 256, 0, stream>>>(Qb, Kb, Vtb, ctx);
    gemm1_kernel<<<dim3(512), 512, 0, stream>>>(ctx, Wt + 3 * 1024 * 1024,
                                                bo, out);
}